// Round 8
// baseline (29745.108 us; speedup 1.0000x reference)
//
#include <hip/hip_runtime.h>
#include <hip/hip_bf16.h>
#include <stdint.h>

// ESN: out[t] = tanh(U[t] + W_res @ s_{t-1}), T=16384 sequential steps.
// Kernel 1: U = X@W_in^T into d_out in place.
// Kernel 2: 8 worker blocks x 1024 threads claimed on ONE XCD via XCC_ID
// pigeonhole (proven). Transport v8 = R7's 64-bit pair-slot tag poll with
// ONE change: each pair-slot PADDED TO ITS OWN 64B LINE.
// Evidence chain: R7 halved RMW count vs R0 -> only -5%. Both layouts had
// ~56 atomic ops per 64B line per round (R0: 8192/128 lines, R7: 3584/64)
// -- L2 line-lock serialization makes ops-per-line, not total ops, the
// binding resource (~900-2000cy queueing/step = the unexplained residual).
// v8: 1 poller per line, 0 line contention -> poll round drains in ~224cy.
// Packet: {24-bit rounded fp32 | 8-bit step tag} dword; rows {2i, 2i+1}
// live in dwords 0-1 of line i; poller i reads both with ONE
// global_atomic_add_x2 (sc0, add 0) -- the only load primitive proven
// coherent with remote plain stores on gfx950 (R4). Own-block rows skipped
// (producer writes sbuf directly). Everything else is R7-verbatim.

constexpr int T_N = 16384;
constexpr int R_N = 1024;
constexpr int I_N = 128;

// ---------------------------------------------------------------- kernel 1
constexpr int BT = 64, BR = 64;

__global__ __launch_bounds__(256) void gemm_u_kernel(
    const float* __restrict__ X, const float* __restrict__ Win,
    float* __restrict__ U)
{
    __shared__ float XS[BT][68];
    __shared__ float WS[BR][68];
    const int tid = threadIdx.x;
    const int ty = tid >> 4, tx = tid & 15;
    const int t0 = blockIdx.x * BT;
    const int r0 = blockIdx.y * BR;
    float acc[4][4] = {};

    for (int k0 = 0; k0 < I_N; k0 += 64) {
        for (int idx = tid; idx < BT * 16; idx += 256) {
            int row = idx >> 4, c4 = (idx & 15) << 2;
            *reinterpret_cast<float4*>(&XS[row][c4]) =
                *reinterpret_cast<const float4*>(&X[(size_t)(t0 + row) * I_N + k0 + c4]);
        }
        for (int idx = tid; idx < BR * 16; idx += 256) {
            int row = idx >> 4, c4 = (idx & 15) << 2;
            *reinterpret_cast<float4*>(&WS[row][c4]) =
                *reinterpret_cast<const float4*>(&Win[(size_t)(r0 + row) * I_N + k0 + c4]);
        }
        __syncthreads();
#pragma unroll
        for (int k = 0; k < 64; k += 4) {
            float4 a[4], b[4];
#pragma unroll
            for (int i = 0; i < 4; ++i)
                a[i] = *reinterpret_cast<const float4*>(&XS[ty + 16 * i][k]);
#pragma unroll
            for (int jj = 0; jj < 4; ++jj)
                b[jj] = *reinterpret_cast<const float4*>(&WS[tx + 16 * jj][k]);
#pragma unroll
            for (int i = 0; i < 4; ++i)
#pragma unroll
                for (int jj = 0; jj < 4; ++jj)
                    acc[i][jj] += a[i].x * b[jj].x + a[i].y * b[jj].y +
                                  a[i].z * b[jj].z + a[i].w * b[jj].w;
        }
        __syncthreads();
    }
#pragma unroll
    for (int i = 0; i < 4; ++i)
#pragma unroll
        for (int jj = 0; jj < 4; ++jj)
            U[(size_t)(t0 + ty + 16 * i) * R_N + (r0 + tx + 16 * jj)] = acc[i][jj];
}

// ---------------------------------------------------------------- kernel 2
constexpr int GBLK    = 8;             // worker blocks (one XCD)
constexpr int NLAUNCH = 64;            // pigeonhole: some XCD collects 8
constexpr int B2      = 1024;          // threads per block
constexpr int RPB     = R_N / GBLK;    // 128 rows per block
constexpr int TPR     = 8;             // threads per row
constexpr int KMAX    = 96;            // nnz/row cap (validated r1..r5)
constexpr int NSL     = KMAX / TPR;    // 12 register slots per thread
constexpr int NSLOT   = R_N / 2;       // 512 pair-slots per parity
constexpr int LINE64  = 8;             // u64 words per 64B line
constexpr int PCAP    = 1 << 20;       // anti-hang cap

__device__ __forceinline__ float fast_tanh(float x) {
    float ax = fabsf(x);
    float e  = __expf(-2.0f * ax);
    float y  = (1.0f - e) / (1.0f + e);
    return copysignf(y, x);
}

// SE-scope 64-bit atomic add 0 with return: executes at the XCD L2 -- the
// only load primitive proven coherent with remote plain stores (R0/R4).
__device__ __forceinline__ unsigned long long l2_atomic_read64(
    unsigned long long* addr)
{
    unsigned long long old;
    asm volatile("global_atomic_add_x2 %0, %1, %2, off sc0\n\t"
                 "s_waitcnt vmcnt(0)"
                 : "=v"(old) : "v"(addr), "v"(0ull) : "memory");
    return old;
}

// plain 4B store: dirty line in the shared XCD L2 (visible to sc0 RMWs)
__device__ __forceinline__ void l2_store_u32(uint32_t* addr, uint32_t v) {
    asm volatile("global_store_dword %0, %1, off"
                 :: "v"(addr), "v"(v) : "memory");
}

__global__ __launch_bounds__(1024) void esn_scan_kernel(
    const float* __restrict__ Wres, const float* __restrict__ state0,
    float* out, uint32_t* hdr, unsigned long long* slots)
{
    __shared__ int   s_role;
    __shared__ float sbuf[2][R_N];        // 8 KB ping-pong state
    __shared__ uint2 ell[RPB][KMAX];      // 96 KB (col, val-bits)
    __shared__ int   cnt[RPB];

    const int tid = threadIdx.x;

    // ---- claim: first XCD to collect 8 blocks wins (proven mechanism)
    if (tid == 0) {
        uint32_t xcd;
        asm volatile("s_getreg_b32 %0, hwreg(HW_REG_XCC_ID)" : "=s"(xcd));
        xcd &= 7u;
        uint32_t rank = __hip_atomic_fetch_add(&hdr[xcd], 1u,
                            __ATOMIC_RELAXED, __HIP_MEMORY_SCOPE_AGENT);
        int role = -1;
        if (rank < (uint32_t)GBLK) {
            if (rank == (uint32_t)(GBLK - 1)) {
                uint32_t expected = 0u;
                __hip_atomic_compare_exchange_strong(&hdr[8], &expected, xcd + 1u,
                    __ATOMIC_RELAXED, __ATOMIC_RELAXED, __HIP_MEMORY_SCOPE_AGENT);
            }
            uint32_t win = 0; int sp = 0;
            do {
                win = __hip_atomic_load(&hdr[8], __ATOMIC_RELAXED,
                                        __HIP_MEMORY_SCOPE_AGENT);
            } while (win == 0u && ++sp < PCAP);
            if (win == xcd + 1u) role = (int)rank;
        }
        s_role = role;
    }
    __syncthreads();
    const int b = s_role;
    if (b < 0) return;
    const int row0 = b * RPB;

    // ---- one-time: extract this block's sparse rows from dense W_res
    if (tid < RPB) cnt[tid] = 0;
    __syncthreads();
    for (int idx = tid; idx < RPB * R_N; idx += B2) {     // coalesced scan
        int r = idx >> 10, c = idx & (R_N - 1);
        float w = Wres[(size_t)(row0 + r) * R_N + c];
        if (w != 0.0f) {
            int slot = atomicAdd(&cnt[r], 1);
            if (slot < KMAX) ell[r][slot] = make_uint2((uint32_t)c, __float_as_uint(w));
        }
    }
    __syncthreads();

    // ---- hoist my slots into registers (R0-verbatim predicated layout)
    const int rloc = tid >> 3;            // local row 0..127
    const int j    = tid & 7;             // 0..7
    const int row  = row0 + rloc;
    int   cols[NSL];
    float vals[NSL];
    int   kcnt;
    {
        int myn = cnt[rloc];
        if (myn > KMAX) myn = KMAX;
        kcnt = (myn > j) ? (((myn - 1 - j) >> 3) + 1) : 0;
#pragma unroll
        for (int k = 0; k < NSL; ++k) {
            int slot = j + k * TPR;
            if (slot < myn) {
                uint2 e = ell[rloc][slot];
                cols[k] = (int)e.x;
                vals[k] = __uint_as_float(e.y);
            } else { cols[k] = 0; vals[k] = 0.0f; }
        }
    }

    sbuf[1][tid] = state0[tid];                   // seed parity (t-1)&1 @ t=0
    float u_cur = (j == 0) ? out[row] : 0.0f;
    __syncthreads();

    // pair-slot poller: tid<512 handles rows {2*tid, 2*tid+1} living in the
    // first 8B of line tid; one poller per 64B line (zero line contention)
    const bool poller = (tid < NSLOT) && ((tid >> 6) != b);
    uint32_t* const slots4 = (uint32_t*)slots;    // dword view (producer side)

    // ---- sequential scan: poll -> sbuf -> ONE barrier -> gather -> publish
    for (int t = 0; t < T_N; ++t) {
        const int p = (t - 1) & 1;

        float u_next = 0.0f;
        if (j == 0 && t + 1 < T_N) u_next = out[(size_t)(t + 1) * R_N + row];

        if (t > 0 && poller) {
            // parity stride = NSLOT lines * 8 u64 = 4096 u64 words
            unsigned long long* slot =
                slots + ((size_t)p << 12) + ((size_t)tid << 3);
            const uint32_t want8 = (uint32_t)(t & 0xFF);  // s_{t-1} tag
            const unsigned long long want2 =
                (unsigned long long)want8 | ((unsigned long long)want8 << 32);
            const unsigned long long tmask = 0x000000FF000000FFull;
            unsigned long long w; int sp = 0;
            do { w = l2_atomic_read64(slot);      // 2 rows per RMW, own line
            } while (((w ^ want2) & tmask) != 0ull && ++sp < PCAP);
            float2 st;
            st.x = __uint_as_float((uint32_t)w & 0xFFFFFF00u);
            st.y = __uint_as_float((uint32_t)(w >> 32) & 0xFFFFFF00u);
            *reinterpret_cast<float2*>(&sbuf[p][tid << 1]) = st;  // ds_write_b64
        }
        __syncthreads();                  // sbuf[p] complete

        const float* sb = sbuf[p];
        float acc = 0.0f;
#pragma unroll
        for (int k = 0; k < NSL; ++k)
            if (k < kcnt) acc = fmaf(vals[k], sb[cols[k]], acc);

        acc += __shfl_xor(acc, 1, TPR);
        acc += __shfl_xor(acc, 2, TPR);
        acc += __shfl_xor(acc, 4, TPR);

        if (j == 0) {
            float y = fast_tanh(u_cur + acc);
            uint32_t bits = __float_as_uint(y);
            uint32_t pkt  = ((bits + 0x80u) & 0xFFFFFF00u)   // round to 24b
                          | ((uint32_t)(t + 1) & 0xFFu);
            // publish FIRST: consumer-visible latency off the critical path.
            // row r -> line r>>1 (16 dwords), dword (r&1); parity stride
            // = NSLOT * 16 dwords = 8192 dwords.
            l2_store_u32(slots4 + ((size_t)(t & 1) << 13)
                               + ((size_t)(row >> 1) << 4) + (row & 1), pkt);
            out[(size_t)t * R_N + row] = y;
            sbuf[t & 1][row] = y;                        // own-row fast path
        }
        u_cur = u_next;
        // sbuf[p] reuse safety: consumers read sbuf[p] in gather(t) before
        // their poll-write(t+2) which sits after barrier(t+1) -> one
        // barrier/step suffices. Tag aliasing (mod 256) needs 128-step
        // producer/consumer skew; actual skew <2 steps by data dependency.
    }
}

// ---------------------------------------------------------------- launcher
extern "C" void kernel_launch(void* const* d_in, const int* in_sizes, int n_in,
                              void* d_out, int out_size, void* d_ws, size_t ws_size,
                              hipStream_t stream)
{
    const float* X      = (const float*)d_in[0];   // (T, I)
    const float* W_in   = (const float*)d_in[1];   // (R, I)
    const float* W_res  = (const float*)d_in[2];   // (R, R)
    const float* state0 = (const float*)d_in[3];   // (R,)
    float* out = (float*)d_out;                    // (T, R)

    uint32_t* hdr = (uint32_t*)d_ws;                          // 1 KB header
    unsigned long long* slots =
        (unsigned long long*)((char*)d_ws + 1024);   // 2 x 512 lines x 64B

    // zero header + padded ring slots (harness poisons ws with 0xAA)
    hipMemsetAsync(d_ws, 0, 1024 + (size_t)2 * NSLOT * 64, stream);

    dim3 g1(T_N / BT, R_N / BR);
    gemm_u_kernel<<<g1, 256, 0, stream>>>(X, W_in, out);

    esn_scan_kernel<<<NLAUNCH, B2, 0, stream>>>(W_res, state0, out, hdr, slots);
}

// Round 9
// 24921.806 us; speedup vs baseline: 1.1935x; 1.1935x over previous
//
#include <hip/hip_runtime.h>
#include <hip/hip_bf16.h>
#include <stdint.h>

// ESN: out[t] = tanh(U[t] + W_res @ s_{t-1}), T=16384 sequential steps.
// Kernel 1: U = X@W_in^T into d_out in place.
// Kernel 2: 8 worker blocks x 1024 threads claimed on ONE XCD via XCC_ID
// pigeonhole (proven). Transport v9 = R7's 64-bit pair-slot tag poll
// (UNPADDED layout -- R8's line padding refuted: +30% dur, 3.5x WRITE)
// with ONE change: the poll primitive is global_atomic_CMPSWAP_x2 with
// cmp==src==0 instead of atomic_add 0.
// Evidence chain (R7/R8): every sc0 atomic RMW write-throughs a sector
// toward HBM (WRITE_SIZE tracks RMW count x sector dispersion; R8's
// padded slots -> 143KB/step HBM writes and +1040 cyc/step). add(0)
// writes unconditionally -> HBM write-commit sits in the poll RTT.
// A FAILED cmpswap performs NO write (pure L2 read, same coherent-at-L2
// semantics); it can only "succeed" when the slot still holds 0
// (pre-seed), writing 0 = no-op. So: zero dirty-line churn, zero
// write-queue occupancy, unchanged read coherence.
// Packet: {24-bit rounded fp32 | 8-bit step tag} dword; rows {2i,2i+1} in
// dwords {0,1} of u64 slot i; producer publishes with a plain dword store
// (dirty in shared L2, proven); consumers poll pairs, check both tags,
// ds_write_b64 into sbuf. Own-block rows skipped (producer writes sbuf).

constexpr int T_N = 16384;
constexpr int R_N = 1024;
constexpr int I_N = 128;

// ---------------------------------------------------------------- kernel 1
constexpr int BT = 64, BR = 64;

__global__ __launch_bounds__(256) void gemm_u_kernel(
    const float* __restrict__ X, const float* __restrict__ Win,
    float* __restrict__ U)
{
    __shared__ float XS[BT][68];
    __shared__ float WS[BR][68];
    const int tid = threadIdx.x;
    const int ty = tid >> 4, tx = tid & 15;
    const int t0 = blockIdx.x * BT;
    const int r0 = blockIdx.y * BR;
    float acc[4][4] = {};

    for (int k0 = 0; k0 < I_N; k0 += 64) {
        for (int idx = tid; idx < BT * 16; idx += 256) {
            int row = idx >> 4, c4 = (idx & 15) << 2;
            *reinterpret_cast<float4*>(&XS[row][c4]) =
                *reinterpret_cast<const float4*>(&X[(size_t)(t0 + row) * I_N + k0 + c4]);
        }
        for (int idx = tid; idx < BR * 16; idx += 256) {
            int row = idx >> 4, c4 = (idx & 15) << 2;
            *reinterpret_cast<float4*>(&WS[row][c4]) =
                *reinterpret_cast<const float4*>(&Win[(size_t)(r0 + row) * I_N + k0 + c4]);
        }
        __syncthreads();
#pragma unroll
        for (int k = 0; k < 64; k += 4) {
            float4 a[4], b[4];
#pragma unroll
            for (int i = 0; i < 4; ++i)
                a[i] = *reinterpret_cast<const float4*>(&XS[ty + 16 * i][k]);
#pragma unroll
            for (int jj = 0; jj < 4; ++jj)
                b[jj] = *reinterpret_cast<const float4*>(&WS[tx + 16 * jj][k]);
#pragma unroll
            for (int i = 0; i < 4; ++i)
#pragma unroll
                for (int jj = 0; jj < 4; ++jj)
                    acc[i][jj] += a[i].x * b[jj].x + a[i].y * b[jj].y +
                                  a[i].z * b[jj].z + a[i].w * b[jj].w;
        }
        __syncthreads();
    }
#pragma unroll
    for (int i = 0; i < 4; ++i)
#pragma unroll
        for (int jj = 0; jj < 4; ++jj)
            U[(size_t)(t0 + ty + 16 * i) * R_N + (r0 + tx + 16 * jj)] = acc[i][jj];
}

// ---------------------------------------------------------------- kernel 2
constexpr int GBLK    = 8;             // worker blocks (one XCD)
constexpr int NLAUNCH = 64;            // pigeonhole: some XCD collects 8
constexpr int B2      = 1024;          // threads per block
constexpr int RPB     = R_N / GBLK;    // 128 rows per block
constexpr int TPR     = 8;             // threads per row
constexpr int KMAX    = 96;            // nnz/row cap (validated r1..r5)
constexpr int NSL     = KMAX / TPR;    // 12 register slots per thread
constexpr int NSLOT   = R_N / 2;       // 512 pair-slots per parity
constexpr int PCAP    = 1 << 20;       // anti-hang cap

__device__ __forceinline__ float fast_tanh(float x) {
    float ax = fabsf(x);
    float e  = __expf(-2.0f * ax);
    float y  = (1.0f - e) / (1.0f + e);
    return copysignf(y, x);
}

// Read-mostly coherent 64-bit poll: cmpswap with cmp==src==0. Executes at
// the XCD L2 (coherent with remote plain stores, same path as the proven
// atomic_add-0); on compare FAIL (any published packet != 0) performs NO
// write -> no dirty line, no HBM write-through in the RTT.
__device__ __forceinline__ unsigned long long l2_cas_read64(
    unsigned long long* addr)
{
    using u64x2 = __attribute__((ext_vector_type(2))) unsigned long long;
    u64x2 sc;                 // [0]=src, [1]=cmp -- both 0
    sc[0] = 0ull; sc[1] = 0ull;
    unsigned long long old;
    asm volatile("global_atomic_cmpswap_x2 %0, %1, %2, off sc0\n\t"
                 "s_waitcnt vmcnt(0)"
                 : "=v"(old) : "v"(addr), "v"(sc) : "memory");
    return old;
}

// plain 4B store: dirty line in the shared XCD L2 (visible to sc0 RMWs)
__device__ __forceinline__ void l2_store_u32(uint32_t* addr, uint32_t v) {
    asm volatile("global_store_dword %0, %1, off"
                 :: "v"(addr), "v"(v) : "memory");
}

__global__ __launch_bounds__(1024) void esn_scan_kernel(
    const float* __restrict__ Wres, const float* __restrict__ state0,
    float* out, uint32_t* hdr, unsigned long long* slots)
{
    __shared__ int   s_role;
    __shared__ float sbuf[2][R_N];        // 8 KB ping-pong state
    __shared__ uint2 ell[RPB][KMAX];      // 96 KB (col, val-bits)
    __shared__ int   cnt[RPB];

    const int tid = threadIdx.x;

    // ---- claim: first XCD to collect 8 blocks wins (proven mechanism)
    if (tid == 0) {
        uint32_t xcd;
        asm volatile("s_getreg_b32 %0, hwreg(HW_REG_XCC_ID)" : "=s"(xcd));
        xcd &= 7u;
        uint32_t rank = __hip_atomic_fetch_add(&hdr[xcd], 1u,
                            __ATOMIC_RELAXED, __HIP_MEMORY_SCOPE_AGENT);
        int role = -1;
        if (rank < (uint32_t)GBLK) {
            if (rank == (uint32_t)(GBLK - 1)) {
                uint32_t expected = 0u;
                __hip_atomic_compare_exchange_strong(&hdr[8], &expected, xcd + 1u,
                    __ATOMIC_RELAXED, __ATOMIC_RELAXED, __HIP_MEMORY_SCOPE_AGENT);
            }
            uint32_t win = 0; int sp = 0;
            do {
                win = __hip_atomic_load(&hdr[8], __ATOMIC_RELAXED,
                                        __HIP_MEMORY_SCOPE_AGENT);
            } while (win == 0u && ++sp < PCAP);
            if (win == xcd + 1u) role = (int)rank;
        }
        s_role = role;
    }
    __syncthreads();
    const int b = s_role;
    if (b < 0) return;
    const int row0 = b * RPB;

    // ---- one-time: extract this block's sparse rows from dense W_res
    if (tid < RPB) cnt[tid] = 0;
    __syncthreads();
    for (int idx = tid; idx < RPB * R_N; idx += B2) {     // coalesced scan
        int r = idx >> 10, c = idx & (R_N - 1);
        float w = Wres[(size_t)(row0 + r) * R_N + c];
        if (w != 0.0f) {
            int slot = atomicAdd(&cnt[r], 1);
            if (slot < KMAX) ell[r][slot] = make_uint2((uint32_t)c, __float_as_uint(w));
        }
    }
    __syncthreads();

    // ---- hoist my slots into registers (R0-verbatim predicated layout)
    const int rloc = tid >> 3;            // local row 0..127
    const int j    = tid & 7;             // 0..7
    const int row  = row0 + rloc;
    int   cols[NSL];
    float vals[NSL];
    int   kcnt;
    {
        int myn = cnt[rloc];
        if (myn > KMAX) myn = KMAX;
        kcnt = (myn > j) ? (((myn - 1 - j) >> 3) + 1) : 0;
#pragma unroll
        for (int k = 0; k < NSL; ++k) {
            int slot = j + k * TPR;
            if (slot < myn) {
                uint2 e = ell[rloc][slot];
                cols[k] = (int)e.x;
                vals[k] = __uint_as_float(e.y);
            } else { cols[k] = 0; vals[k] = 0.0f; }
        }
    }

    sbuf[1][tid] = state0[tid];                   // seed parity (t-1)&1 @ t=0
    float u_cur = (j == 0) ? out[row] : 0.0f;
    __syncthreads();

    // pair-slot poller: tid<512 handles rows {2*tid, 2*tid+1}; skip own block
    const bool poller = (tid < NSLOT) && ((tid >> 6) != b);
    uint32_t* const slots4 = (uint32_t*)slots;    // dword view (producer side)

    // ---- sequential scan: poll -> sbuf -> ONE barrier -> gather -> publish
    for (int t = 0; t < T_N; ++t) {
        const int p = (t - 1) & 1;

        float u_next = 0.0f;
        if (j == 0 && t + 1 < T_N) u_next = out[(size_t)(t + 1) * R_N + row];

        if (t > 0 && poller) {
            unsigned long long* slot = slots + ((size_t)p << 9) + tid;
            const uint32_t want8 = (uint32_t)(t & 0xFF);  // s_{t-1} tag
            const unsigned long long want2 =
                (unsigned long long)want8 | ((unsigned long long)want8 << 32);
            const unsigned long long tmask = 0x000000FF000000FFull;
            unsigned long long w; int sp = 0;
            do { w = l2_cas_read64(slot);         // 2 rows per CAS, no write
            } while (((w ^ want2) & tmask) != 0ull && ++sp < PCAP);
            float2 st;
            st.x = __uint_as_float((uint32_t)w & 0xFFFFFF00u);
            st.y = __uint_as_float((uint32_t)(w >> 32) & 0xFFFFFF00u);
            *reinterpret_cast<float2*>(&sbuf[p][tid << 1]) = st;  // ds_write_b64
        }
        __syncthreads();                  // sbuf[p] complete

        const float* sb = sbuf[p];
        float acc = 0.0f;
#pragma unroll
        for (int k = 0; k < NSL; ++k)
            if (k < kcnt) acc = fmaf(vals[k], sb[cols[k]], acc);

        acc += __shfl_xor(acc, 1, TPR);
        acc += __shfl_xor(acc, 2, TPR);
        acc += __shfl_xor(acc, 4, TPR);

        if (j == 0) {
            float y = fast_tanh(u_cur + acc);
            uint32_t bits = __float_as_uint(y);
            uint32_t pkt  = ((bits + 0x80u) & 0xFFFFFF00u)   // round to 24b
                          | ((uint32_t)(t + 1) & 0xFFu);
            // publish FIRST: consumer-visible latency off the critical path
            l2_store_u32(slots4 + ((size_t)(t & 1) << 10) + row, pkt);
            out[(size_t)t * R_N + row] = y;
            sbuf[t & 1][row] = y;                        // own-row fast path
        }
        u_cur = u_next;
        // sbuf[p] reuse safety: consumers read sbuf[p] in gather(t) before
        // their poll-write(t+2) which sits after barrier(t+1) -> one
        // barrier/step suffices. Tag aliasing (mod 256) needs 128-step
        // producer/consumer skew; actual skew <2 steps by data dependency.
    }
}

// ---------------------------------------------------------------- launcher
extern "C" void kernel_launch(void* const* d_in, const int* in_sizes, int n_in,
                              void* d_out, int out_size, void* d_ws, size_t ws_size,
                              hipStream_t stream)
{
    const float* X      = (const float*)d_in[0];   // (T, I)
    const float* W_in   = (const float*)d_in[1];   // (R, I)
    const float* W_res  = (const float*)d_in[2];   // (R, R)
    const float* state0 = (const float*)d_in[3];   // (R,)
    float* out = (float*)d_out;                    // (T, R)

    uint32_t* hdr = (uint32_t*)d_ws;                          // 1 KB header
    unsigned long long* slots =
        (unsigned long long*)((char*)d_ws + 1024);            // 2 x 512 x 8B

    // zero header + ring slots (harness poisons ws with 0xAA each launch)
    hipMemsetAsync(d_ws, 0, 1024 + (size_t)2 * NSLOT * sizeof(unsigned long long),
                   stream);

    dim3 g1(T_N / BT, R_N / BR);
    gemm_u_kernel<<<g1, 256, 0, stream>>>(X, W_in, out);

    esn_scan_kernel<<<NLAUNCH, B2, 0, stream>>>(W_res, state0, out, hdr, slots);
}